// Round 1
// baseline (356.402 us; speedup 1.0000x reference)
//
#include <hip/hip_runtime.h>
#include <hip/hip_bf16.h>

// SupPixPool: out[b,c,k] = max over pixels p with spx[b,p]==k of img[b,c,p].
// B=4, C=64, H=W=512, K=1024.
//
// Round-6: R5 structure (channels-across-lanes, padded stride-9 LDS table,
// depth-1 prefetch pipeline, nontemporal img loads) + READ-FILTERED LDS
// atomics. Theory: pool_partial is LDS-atomic-throughput-bound (~67M
// ds_max_u32 lane-ops serialized per active lane, ~300 of the 353 us), not
// memory-bound (roofline ~52 us). atomicMax is monotone, so "read current,
// skip atomic if already >= value" is race-safe and drops expected update
// fraction to H(16)/16 ~ 21% -> the exec-masked ds_max issues with ~13/64
// active lanes instead of 64. ds_read_b32 is bank-parallel and cheap, so the
// filter costs ~10-15 us and should save ~200 us if the theory is right.

constexpr int Kseg = 1024;
constexpr int Bn   = 4;
constexpr int Cn   = 64;
constexpr int HWn  = 512 * 512;

constexpr int CH     = 8;             // channels per block
constexpr int NCG    = Cn / CH;       // 8
constexpr int TPB    = 1024;
constexpr int NCHUNK = 16;            // pixel chunks per (b, cg)
constexpr int PIX    = HWn / NCHUNK;  // 16384 pixels per block
constexpr int STR    = 9;             // padded table stride (36 KB)
constexpr int TBLW   = Kseg * STR;    // 9216 words
constexpr int NBLK   = Bn * NCG * NCHUNK;  // 512
constexpr int QPT    = TPB / CH;      // 128 pixel-quads in flight
constexpr int ITERS  = PIX / (QPT * 4);    // 32

typedef float  vf4 __attribute__((ext_vector_type(4)));
typedef int    vi4 __attribute__((ext_vector_type(4)));

// order-preserving float->uint encoding: enc monotonic, unsigned max == fmax
constexpr unsigned ENEG = 0x007FFFFFu;  // enc(-inf)

__device__ __forceinline__ unsigned enc(float f) {
    unsigned u = __float_as_uint(f);
    return u ^ ((unsigned)((int)u >> 31) | 0x80000000u);
}
__device__ __forceinline__ float dec(unsigned e) {
    unsigned u = (e & 0x80000000u) ? (e ^ 0x80000000u) : ~e;
    return __uint_as_float(u);
}

__global__ __launch_bounds__(TPB, 8) void pool_partial(
    const float* __restrict__ img, const int* __restrict__ spx,
    unsigned* __restrict__ part) {
    __shared__ unsigned tbl[TBLW];  // 36 KB, [k][9] padded

    const int bx    = blockIdx.x;
    const int chunk = bx % NCHUNK;
    const int cg    = (bx / NCHUNK) % NCG;
    const int b     = bx / (NCHUNK * NCG);

    for (int i = threadIdx.x; i < TBLW; i += TPB) tbl[i] = ENEG;
    __syncthreads();

    const int c  = threadIdx.x & (CH - 1);   // channel lane 0..7
    const int pq = threadIdx.x >> 3;         // pixel-quad lane 0..127

    const float* imgc = img + ((size_t)(b * Cn + cg * CH + c)) * HWn
                            + (size_t)chunk * PIX;
    const int*   spxb = spx + (size_t)b * HWn + (size_t)chunk * PIX;

    // explicit depth-1 pipeline: loads for it+1 issued before atomics of it
    vf4 v = __builtin_nontemporal_load((const vf4*)(imgc + 4 * pq));
    vi4 k = *(const vi4*)(spxb + 4 * pq);

#pragma unroll 4
    for (int it = 0; it < ITERS; ++it) {
        vf4 vn;
        vi4 kn;
        if (it + 1 < ITERS) {
            const int qn = pq + (it + 1) * QPT;
            vn = __builtin_nontemporal_load((const vf4*)(imgc + 4 * qn));
            kn = *(const vi4*)(spxb + 4 * qn);
        }
        const int kx = (k.x & (Kseg - 1)) * STR + c;
        const int ky = (k.y & (Kseg - 1)) * STR + c;
        const int kz = (k.z & (Kseg - 1)) * STR + c;
        const int kw = (k.w & (Kseg - 1)) * STR + c;
        const unsigned ex = enc(v.x);
        const unsigned ey = enc(v.y);
        const unsigned ez = enc(v.z);
        const unsigned ew = enc(v.w);
        // read-filter: monotone max -> skipping when tbl already >= e is
        // race-safe. Cuts active lanes in the ds_max from 64 to ~13.
        const unsigned cx = tbl[kx];
        const unsigned cy = tbl[ky];
        const unsigned cz = tbl[kz];
        const unsigned cw = tbl[kw];
        if (ex > cx) atomicMax(tbl + kx, ex);
        if (ey > cy) atomicMax(tbl + ky, ey);
        if (ez > cz) atomicMax(tbl + kz, ez);
        if (ew > cw) atomicMax(tbl + kw, ew);
        v = vn;
        k = kn;
    }
    __syncthreads();

    unsigned* dst = part + (size_t)bx * TBLW;
    for (int i = threadIdx.x; i < TBLW; i += TPB) dst[i] = tbl[i];
}

__global__ __launch_bounds__(256) void pool_reduce(
    const unsigned* __restrict__ part, float* __restrict__ out) {
    const int gid = blockIdx.x * 256 + threadIdx.x;  // [0, B*C*K)
    const int k  = gid & (Kseg - 1);
    const int cc = (gid >> 10) & (Cn - 1);
    const int b  = gid >> 16;
    const int cg = cc >> 3, j = cc & (CH - 1);

    unsigned acc = ENEG;
    const unsigned* p = part
        + ((size_t)(b * NCG + cg) * NCHUNK) * TBLW + k * STR + j;
    for (int ch = 0; ch < NCHUNK; ++ch)
        acc = max(acc, p[(size_t)ch * TBLW]);
    out[gid] = dec(acc);
}

// -------- fallback path (ws too small): global atomic merge into d_out -----
__global__ __launch_bounds__(256) void init_enc_k(unsigned* __restrict__ o) {
    o[blockIdx.x * 256 + threadIdx.x] = ENEG;
}

__global__ __launch_bounds__(TPB, 8) void pool_atomic(
    const float* __restrict__ img, const int* __restrict__ spx,
    unsigned* __restrict__ gtab) {
    __shared__ unsigned tbl[TBLW];

    const int bx    = blockIdx.x;
    const int chunk = bx % NCHUNK;
    const int cg    = (bx / NCHUNK) % NCG;
    const int b     = bx / (NCHUNK * NCG);

    for (int i = threadIdx.x; i < TBLW; i += TPB) tbl[i] = ENEG;
    __syncthreads();

    const int c  = threadIdx.x & (CH - 1);
    const int pq = threadIdx.x >> 3;

    const float* imgc = img + ((size_t)(b * Cn + cg * CH + c)) * HWn
                            + (size_t)chunk * PIX;
    const int*   spxb = spx + (size_t)b * HWn + (size_t)chunk * PIX;

#pragma unroll 4
    for (int it = 0; it < ITERS; ++it) {
        const int q = pq + it * QPT;
        const vf4 v = *(const vf4*)(imgc + 4 * q);
        vi4 k = *(const vi4*)(spxb + 4 * q);
        const int kx = (k.x & (Kseg - 1)) * STR + c;
        const int ky = (k.y & (Kseg - 1)) * STR + c;
        const int kz = (k.z & (Kseg - 1)) * STR + c;
        const int kw = (k.w & (Kseg - 1)) * STR + c;
        const unsigned ex = enc(v.x);
        const unsigned ey = enc(v.y);
        const unsigned ez = enc(v.z);
        const unsigned ew = enc(v.w);
        const unsigned cx = tbl[kx];
        const unsigned cy = tbl[ky];
        const unsigned cz = tbl[kz];
        const unsigned cw = tbl[kw];
        if (ex > cx) atomicMax(tbl + kx, ex);
        if (ey > cy) atomicMax(tbl + ky, ey);
        if (ez > cz) atomicMax(tbl + kz, ez);
        if (ew > cw) atomicMax(tbl + kw, ew);
    }
    __syncthreads();

    // tbl[k*STR + j] -> out index (b*Cn + cg*CH + j)*K + k
    unsigned* base = gtab + (size_t)(b * Cn + cg * CH) * Kseg;
    for (int i = threadIdx.x; i < Kseg * CH; i += TPB) {
        const int k = i >> 3, j = i & (CH - 1);
        const unsigned tv = tbl[k * STR + j];
        unsigned* dst = base + (size_t)j * Kseg + k;
        if (tv > *dst) atomicMax(dst, tv);
    }
}

__global__ __launch_bounds__(256) void decode_inplace(unsigned* __restrict__ o) {
    const int i = blockIdx.x * 256 + threadIdx.x;
    const unsigned e = o[i];
    ((float*)o)[i] = dec(e);
}

extern "C" void kernel_launch(void* const* d_in, const int* in_sizes, int n_in,
                              void* d_out, int out_size, void* d_ws, size_t ws_size,
                              hipStream_t stream) {
    const float* img = (const float*)d_in[0];
    const int*   spx = (const int*)d_in[1];
    float*       out = (float*)d_out;

    const size_t need = (size_t)NBLK * TBLW * sizeof(unsigned);  // ~18.9 MB
    const int nOut256 = (Bn * Cn * Kseg) / 256;                  // 1024

    if (ws_size >= need) {
        unsigned* part = (unsigned*)d_ws;
        pool_partial<<<NBLK, TPB, 0, stream>>>(img, spx, part);
        pool_reduce<<<nOut256, 256, 0, stream>>>(part, out);
    } else {
        unsigned* gt = (unsigned*)d_out;
        init_enc_k<<<nOut256, 256, 0, stream>>>(gt);
        pool_atomic<<<NBLK, TPB, 0, stream>>>(img, spx, gt);
        decode_inplace<<<nOut256, 256, 0, stream>>>(gt);
    }
}